// Round 5
// baseline (127.029 us; speedup 1.0000x reference)
//
#include <hip/hip_runtime.h>
#include <hip/hip_bf16.h>

#define V_N   40000
#define P_N   32
#define NTOT  (V_N * P_N)            // BN batch positions
#define VXc   0.16f
#define VYc   0.16f
#define XOFF  0.08f                  // VX/2 + 0.0
#define YOFF  (-39.6f)               // VY/2 - 39.68
#define BN_EPS 1e-5f

#define SBLK  1250                   // stats blocks: 5000 waves x 4 iters x 2 voxels
#define PBLK  2500                   // pfn blocks: 10000 waves x 4 voxels
#define CSTR  32                     // counter stride in floats (128 B: own L2 line)
// ws layout: [0, 54*CSTR*4) padded stat counters; means float4 at byte 8192

// 54 moment slots as NAMED SCALARS (arrays fail SROA -> scratch traffic).
#define FOR_S(X) X(0) X(1) X(2) X(3) X(4) X(5) X(6) X(7) X(8)
#define FOR_M(X) \
  X(0,0) X(0,1) X(0,2) X(0,3) X(0,4) X(0,5) X(0,6) X(0,7) X(0,8) \
  X(1,1) X(1,2) X(1,3) X(1,4) X(1,5) X(1,6) X(1,7) X(1,8) \
  X(2,2) X(2,3) X(2,4) X(2,5) X(2,6) X(2,7) X(2,8) \
  X(3,3) X(3,4) X(3,5) X(3,6) X(3,7) X(3,8) \
  X(4,4) X(4,5) X(4,6) X(4,7) X(4,8) \
  X(5,5) X(5,6) X(5,7) X(5,8) \
  X(6,6) X(6,7) X(6,8) \
  X(7,7) X(7,8) \
  X(8,8)

__device__ __forceinline__ float wave_sum(float x) {
#pragma unroll
    for (int m = 1; m < 64; m <<= 1) x += __shfl_xor(x, m, 64);
    return x;
}

__device__ __forceinline__ float rdlane(float x, int l) {
    return __uint_as_float(__builtin_amdgcn_readlane(__float_as_uint(x), l));
}

// ---------------------------------------------------------------------------
// Kernel 1: moment stats + per-voxel xyz means (so pfn needs no cross-lane).
// Wave = 2 voxels/iter (lane&31 = point, lane>>5 = voxel). Coalesced 1 KiB.
// ---------------------------------------------------------------------------
__global__ __launch_bounds__(256) void stats_kernel(
    const float4* __restrict__ voxels,
    const int*    __restrict__ npts_arr,
    const int*    __restrict__ coors,
    float*        __restrict__ stats,    // 54 counters, stride CSTR, pre-zeroed
    float4*       __restrict__ means)    // (V,) per-voxel xyz mean
{
    const int lane = threadIdx.x & 63;
    const int p    = lane & 31;
    const int half = lane >> 5;
    const int gw   = (blockIdx.x * 256 + threadIdx.x) >> 6;
    const int nw   = (SBLK * 256) >> 6;     // 5000 waves

#define DECL_S(i)   float S##i = 0.f;
#define DECL_M(i,j) float M##i##_##j = 0.f;
    FOR_S(DECL_S)
    FOR_M(DECL_M)

    for (int vb = gw * 2; vb < V_N; vb += nw * 2) {
        const int v = vb + half;
        float4 q = voxels[(size_t)v * P_N + p];

        // per-voxel xyz sum over ALL 32 points (reference does not mask here);
        // masks 1..16 stay within each 32-lane half
        float sx = q.x, sy = q.y, sz = q.z;
#pragma unroll
        for (int m = 1; m < 32; m <<= 1) {
            sx += __shfl_xor(sx, m, 64);
            sy += __shfl_xor(sy, m, 64);
            sz += __shfl_xor(sz, m, 64);
        }
        const int   npts = npts_arr[v];
        const float inv  = 1.f / (float)npts;
        const float mx = sx * inv, my = sy * inv, mz = sz * inv;
        const float cx = (float)coors[2 * v]     * VXc + XOFF;
        const float cy = (float)coors[2 * v + 1] * VYc + YOFF;

        if (p == 0) means[v] = make_float4(mx, my, mz, 0.f);

        const float g  = (p < npts) ? 1.f : 0.f;
        const float f0 = q.x * g;
        const float f1 = q.y * g;
        const float f2 = q.z * g;
        const float f3 = q.w * g;
        const float f4 = (q.x - mx) * g;
        const float f5 = (q.y - my) * g;
        const float f6 = (q.z - mz) * g;
        const float f7 = (q.x - cx) * g;
        const float f8 = (q.y - cy) * g;

#define ACC_S(i)   S##i += f##i;
#define ACC_M(i,j) M##i##_##j = fmaf(f##i, f##j, M##i##_##j);
        FOR_S(ACC_S)
        FOR_M(ACC_M)
    }

#define RED_S(i)   S##i = wave_sum(S##i);
#define RED_M(i,j) M##i##_##j = wave_sum(M##i##_##j);
    FOR_S(RED_S)
    FOR_M(RED_M)

    __shared__ float red[4][54];
    const int wib = threadIdx.x >> 6;
    if (lane == 0) {
        float* r = red[wib];
        int k = 0;
#define ST_S(i)   r[k++] = S##i;
#define ST_M(i,j) r[k++] = M##i##_##j;
        FOR_S(ST_S)
        FOR_M(ST_M)
    }
    __syncthreads();
    if (threadIdx.x < 54) {
        float s = red[0][threadIdx.x] + red[1][threadIdx.x]
                + red[2][threadIdx.x] + red[3][threadIdx.x];
        atomicAdd(&stats[threadIdx.x * CSTR], s);   // one line per counter
    }
}

// ---------------------------------------------------------------------------
// Kernel 2: lane = output channel; wave = 2 voxels at a time (A: lanes 0-31
// hold points, B: lanes 32-63). Point broadcast via v_readlane (VALU pipe,
// no LDS). Dynamic uniform trip count = npts (avg 16, no per-point mask).
// ---------------------------------------------------------------------------
__global__ __launch_bounds__(256) void pfn_kernel(
    const float4* __restrict__ voxels,
    const int*    __restrict__ npts_arr,
    const int*    __restrict__ coors,
    const float*  __restrict__ W,        // (64, 9) row-major
    const float*  __restrict__ gamma,
    const float*  __restrict__ beta,
    const float*  __restrict__ stats,    // padded counters
    const float4* __restrict__ means,
    float*        __restrict__ out)      // (V, 64)
{
    const int lane = threadIdx.x & 63;
    const int wib  = threadIdx.x >> 6;

    // ---- BN affine from moment statistics ----
    float w[9];
#pragma unroll
    for (int c = 0; c < 9; ++c) w[c] = W[lane * 9 + c];

    const float invN = 1.f / (float)NTOT;
    float mean = 0.f;
#pragma unroll
    for (int c = 0; c < 9; ++c) mean = fmaf(w[c], stats[c * CSTR], mean);
    mean *= invN;

    float ex2 = 0.f;
    {
        int k = 9;
#pragma unroll
        for (int i = 0; i < 9; ++i)
#pragma unroll
            for (int j = i; j < 9; ++j) {
                const float coef = (i == j) ? 1.f : 2.f;
                ex2 = fmaf(coef * w[i] * w[j], stats[k * CSTR], ex2);
                ++k;
            }
    }
    ex2 *= invN;
    const float var   = ex2 - mean * mean;
    const float scale = gamma[lane] * rsqrtf(var + BN_EPS);
    const float bias  = fmaf(-mean, scale, beta[lane]);

    const float a0 = (w[0] + w[4] + w[7]) * scale;
    const float a1 = (w[1] + w[5] + w[8]) * scale;
    const float a2 = (w[2] + w[6]) * scale;
    const float a3 =  w[3] * scale;
    const float u4 = w[4] * scale, u5 = w[5] * scale, u6 = w[6] * scale;
    const float u7 = w[7] * scale, u8 = w[8] * scale;

    const int gwave = blockIdx.x * 4 + wib;          // 0..9999

#pragma unroll
    for (int it = 0; it < 2; ++it) {
        const int vA = gwave * 4 + it * 2;
        const int vB = vA + 1;

        // lanes 0-31: points of vA; lanes 32-63: points of vB (coalesced 1KiB)
        const int vv = vA + (lane >> 5);
        const float4 q = voxels[(size_t)vv * P_N + (lane & 31)];

        const int nA = __builtin_amdgcn_readfirstlane(npts_arr[vA]);
        const int nB = __builtin_amdgcn_readfirstlane(npts_arr[vB]);

        const float4 mA = means[vA];
        const float4 mB = means[vB];
        const float cxA = (float)coors[2 * vA]     * VXc + XOFF;
        const float cyA = (float)coors[2 * vA + 1] * VYc + YOFF;
        const float cxB = (float)coors[2 * vB]     * VXc + XOFF;
        const float cyB = (float)coors[2 * vB + 1] * VYc + YOFF;

        const float bA = -fmaf(mA.x, u4, fmaf(mA.y, u5, fmaf(mA.z, u6,
                           fmaf(cxA, u7, cyA * u8))));
        const float bB = -fmaf(mB.x, u4, fmaf(mB.y, u5, fmaf(mB.z, u6,
                           fmaf(cxB, u7, cyB * u8))));

        float maxA = -3.4e38f;
#pragma unroll 4
        for (int p = 0; p < nA; ++p) {
            const float tx = rdlane(q.x, p);
            const float ty = rdlane(q.y, p);
            const float tz = rdlane(q.z, p);
            const float tw = rdlane(q.w, p);
            const float d  = fmaf(tx, a0, fmaf(ty, a1, fmaf(tz, a2, tw * a3)));
            maxA = fmaxf(maxA, d);
        }
        float maxB = -3.4e38f;
#pragma unroll 4
        for (int p = 0; p < nB; ++p) {
            const float tx = rdlane(q.x, p + 32);
            const float ty = rdlane(q.y, p + 32);
            const float tz = rdlane(q.z, p + 32);
            const float tw = rdlane(q.w, p + 32);
            const float d  = fmaf(tx, a0, fmaf(ty, a1, fmaf(tz, a2, tw * a3)));
            maxB = fmaxf(maxB, d);
        }

        float mfA = maxA + bA;
        if (nA < P_N) mfA = fmaxf(mfA, 0.f);         // masked rows: x = 0
        out[(size_t)vA * 64 + lane] = fmaxf(mfA + bias, 0.f);

        float mfB = maxB + bB;
        if (nB < P_N) mfB = fmaxf(mfB, 0.f);
        out[(size_t)vB * 64 + lane] = fmaxf(mfB + bias, 0.f);
    }
}

// ---------------------------------------------------------------------------
extern "C" void kernel_launch(void* const* d_in, const int* in_sizes, int n_in,
                              void* d_out, int out_size, void* d_ws, size_t ws_size,
                              hipStream_t stream)
{
    const float4* voxels = (const float4*)d_in[0];
    const int*    npts   = (const int*)d_in[1];
    const int*    coors  = (const int*)d_in[2];
    const float*  W      = (const float*)d_in[3];
    const float*  gamma  = (const float*)d_in[4];
    const float*  beta   = (const float*)d_in[5];
    float*        out    = (float*)d_out;

    float*  stats = (float*)d_ws;                        // padded counters
    float4* means = (float4*)((char*)d_ws + 8192);       // 640 KB

    hipMemsetAsync(stats, 0, 54 * CSTR * sizeof(float), stream);
    stats_kernel<<<SBLK, 256, 0, stream>>>(voxels, npts, coors, stats, means);
    pfn_kernel<<<PBLK, 256, 0, stream>>>(voxels, npts, coors, W, gamma, beta,
                                         stats, means, out);
}

// Round 6
// 119.204 us; speedup vs baseline: 1.0656x; 1.0656x over previous
//
#include <hip/hip_runtime.h>
#include <hip/hip_bf16.h>

#define V_N   40000
#define P_N   32
#define NTOT  (V_N * P_N)            // BN batch positions
#define VXc   0.16f
#define VYc   0.16f
#define XOFF  0.08f                  // VX/2 + 0.0
#define YOFF  (-39.6f)               // VY/2 - 39.68
#define BN_EPS 1e-5f

#define SBLK  250                    // stats: 1000 waves, 20 iters x 2 voxels
#define PBLK  2500                   // pfn: 10000 waves x 4 voxels
#define CSTR  32                     // counter stride in floats (128 B line)
// ws layout: [0, 54*CSTR*4) padded stat counters; means float4 at byte 8192

// 54 moment slots as NAMED SCALARS (arrays fail SROA -> scratch traffic).
#define FOR_S(X) X(0) X(1) X(2) X(3) X(4) X(5) X(6) X(7) X(8)
#define FOR_M(X) \
  X(0,0) X(0,1) X(0,2) X(0,3) X(0,4) X(0,5) X(0,6) X(0,7) X(0,8) \
  X(1,1) X(1,2) X(1,3) X(1,4) X(1,5) X(1,6) X(1,7) X(1,8) \
  X(2,2) X(2,3) X(2,4) X(2,5) X(2,6) X(2,7) X(2,8) \
  X(3,3) X(3,4) X(3,5) X(3,6) X(3,7) X(3,8) \
  X(4,4) X(4,5) X(4,6) X(4,7) X(4,8) \
  X(5,5) X(5,6) X(5,7) X(5,8) \
  X(6,6) X(6,7) X(6,8) \
  X(7,7) X(7,8) \
  X(8,8)

__device__ __forceinline__ float wave_sum(float x) {
#pragma unroll
    for (int m = 1; m < 64; m <<= 1) x += __shfl_xor(x, m, 64);
    return x;
}

__device__ __forceinline__ float rdlane(float x, int l) {
    return __uint_as_float(__builtin_amdgcn_readlane(__float_as_uint(x), l));
}

// ---------------------------------------------------------------------------
// Kernel 1: moment stats + per-voxel xyz means.
// Wave = 2 voxels/iter (lane&31 = point, lane>>5 = voxel). Coalesced 1 KiB.
// Few waves (1000) so the 54x6-level shuffle tail stays ~4 us chip-wide.
// ---------------------------------------------------------------------------
__global__ __launch_bounds__(256) void stats_kernel(
    const float4* __restrict__ voxels,
    const int*    __restrict__ npts_arr,
    const int*    __restrict__ coors,
    float*        __restrict__ stats,    // 54 counters, stride CSTR, pre-zeroed
    float4*       __restrict__ means)    // (V,) per-voxel xyz mean
{
    const int lane = threadIdx.x & 63;
    const int p    = lane & 31;
    const int half = lane >> 5;
    const int gw   = (blockIdx.x * 256 + threadIdx.x) >> 6;
    const int nw   = (SBLK * 256) >> 6;     // 1000 waves

#define DECL_S(i)   float S##i = 0.f;
#define DECL_M(i,j) float M##i##_##j = 0.f;
    FOR_S(DECL_S)
    FOR_M(DECL_M)

    for (int vb = gw * 2; vb < V_N; vb += nw * 2) {
        const int v = vb + half;
        float4 q = voxels[(size_t)v * P_N + p];

        // per-voxel xyz sum over ALL 32 points (reference does not mask here);
        // masks 1..16 stay within each 32-lane half
        float sx = q.x, sy = q.y, sz = q.z;
#pragma unroll
        for (int m = 1; m < 32; m <<= 1) {
            sx += __shfl_xor(sx, m, 64);
            sy += __shfl_xor(sy, m, 64);
            sz += __shfl_xor(sz, m, 64);
        }
        const int   npts = npts_arr[v];
        const float inv  = 1.f / (float)npts;
        const float mx = sx * inv, my = sy * inv, mz = sz * inv;
        const float cx = (float)coors[2 * v]     * VXc + XOFF;
        const float cy = (float)coors[2 * v + 1] * VYc + YOFF;

        if (p == 0) means[v] = make_float4(mx, my, mz, 0.f);

        const float g  = (p < npts) ? 1.f : 0.f;
        const float f0 = q.x * g;
        const float f1 = q.y * g;
        const float f2 = q.z * g;
        const float f3 = q.w * g;
        const float f4 = (q.x - mx) * g;
        const float f5 = (q.y - my) * g;
        const float f6 = (q.z - mz) * g;
        const float f7 = (q.x - cx) * g;
        const float f8 = (q.y - cy) * g;

#define ACC_S(i)   S##i += f##i;
#define ACC_M(i,j) M##i##_##j = fmaf(f##i, f##j, M##i##_##j);
        FOR_S(ACC_S)
        FOR_M(ACC_M)
    }

#define RED_S(i)   S##i = wave_sum(S##i);
#define RED_M(i,j) M##i##_##j = wave_sum(M##i##_##j);
    FOR_S(RED_S)
    FOR_M(RED_M)

    __shared__ float red[4][54];
    const int wib = threadIdx.x >> 6;
    if (lane == 0) {
        float* r = red[wib];
        int k = 0;
#define ST_S(i)   r[k++] = S##i;
#define ST_M(i,j) r[k++] = M##i##_##j;
        FOR_S(ST_S)
        FOR_M(ST_M)
    }
    __syncthreads();
    if (threadIdx.x < 54) {
        float s = red[0][threadIdx.x] + red[1][threadIdx.x]
                + red[2][threadIdx.x] + red[3][threadIdx.x];
        atomicAdd(&stats[threadIdx.x * CSTR], s);   // one line per counter
    }
}

// ---------------------------------------------------------------------------
// Kernel 2: lane = output channel; wave = 2 voxels at a time (A: lanes 0-31
// hold points, B: lanes 32-63). Point broadcast via v_readlane. Dual max
// accumulators (even/odd p) so two independent readlane->fma->max chains
// pipeline instead of one serial chain.
// ---------------------------------------------------------------------------
__global__ __launch_bounds__(256) void pfn_kernel(
    const float4* __restrict__ voxels,
    const int*    __restrict__ npts_arr,
    const int*    __restrict__ coors,
    const float*  __restrict__ W,        // (64, 9) row-major
    const float*  __restrict__ gamma,
    const float*  __restrict__ beta,
    const float*  __restrict__ stats,    // padded counters
    const float4* __restrict__ means,
    float*        __restrict__ out)      // (V, 64)
{
    const int lane = threadIdx.x & 63;
    const int wib  = threadIdx.x >> 6;

    // ---- BN affine from moment statistics ----
    float w[9];
#pragma unroll
    for (int c = 0; c < 9; ++c) w[c] = W[lane * 9 + c];

    const float invN = 1.f / (float)NTOT;
    float mean = 0.f;
#pragma unroll
    for (int c = 0; c < 9; ++c) mean = fmaf(w[c], stats[c * CSTR], mean);
    mean *= invN;

    float ex2 = 0.f;
    {
        int k = 9;
#pragma unroll
        for (int i = 0; i < 9; ++i)
#pragma unroll
            for (int j = i; j < 9; ++j) {
                const float coef = (i == j) ? 1.f : 2.f;
                ex2 = fmaf(coef * w[i] * w[j], stats[k * CSTR], ex2);
                ++k;
            }
    }
    ex2 *= invN;
    const float var   = ex2 - mean * mean;
    const float scale = gamma[lane] * rsqrtf(var + BN_EPS);
    const float bias  = fmaf(-mean, scale, beta[lane]);

    const float a0 = (w[0] + w[4] + w[7]) * scale;
    const float a1 = (w[1] + w[5] + w[8]) * scale;
    const float a2 = (w[2] + w[6]) * scale;
    const float a3 =  w[3] * scale;
    const float u4 = w[4] * scale, u5 = w[5] * scale, u6 = w[6] * scale;
    const float u7 = w[7] * scale, u8 = w[8] * scale;

    const int gwave = blockIdx.x * 4 + wib;          // 0..9999

#define DOT(P_, OFS_) \
    fmaf(rdlane(q.x, (P_) + (OFS_)), a0, \
    fmaf(rdlane(q.y, (P_) + (OFS_)), a1, \
    fmaf(rdlane(q.z, (P_) + (OFS_)), a2, \
         rdlane(q.w, (P_) + (OFS_)) * a3)))

#pragma unroll
    for (int it = 0; it < 2; ++it) {
        const int vA = gwave * 4 + it * 2;
        const int vB = vA + 1;

        // lanes 0-31: points of vA; lanes 32-63: points of vB (coalesced 1KiB)
        const int vv = vA + (lane >> 5);
        const float4 q = voxels[(size_t)vv * P_N + (lane & 31)];

        const int nA = __builtin_amdgcn_readfirstlane(npts_arr[vA]);
        const int nB = __builtin_amdgcn_readfirstlane(npts_arr[vB]);

        const float4 mA = means[vA];
        const float4 mB = means[vB];
        const float cxA = (float)coors[2 * vA]     * VXc + XOFF;
        const float cyA = (float)coors[2 * vA + 1] * VYc + YOFF;
        const float cxB = (float)coors[2 * vB]     * VXc + XOFF;
        const float cyB = (float)coors[2 * vB + 1] * VYc + YOFF;

        const float bA = -fmaf(mA.x, u4, fmaf(mA.y, u5, fmaf(mA.z, u6,
                           fmaf(cxA, u7, cyA * u8))));
        const float bB = -fmaf(mB.x, u4, fmaf(mB.y, u5, fmaf(mB.z, u6,
                           fmaf(cxB, u7, cyB * u8))));

        // voxel A: dual independent chains over even/odd points
        float e0 = -3.4e38f, e1 = -3.4e38f;
        {
            int p = 0;
            for (; p + 1 < nA; p += 2) {
                const float d0 = DOT(p, 0);
                const float d1 = DOT(p + 1, 0);
                e0 = fmaxf(e0, d0);
                e1 = fmaxf(e1, d1);
            }
            if (p < nA) e0 = fmaxf(e0, DOT(p, 0));
        }
        float mfA = fmaxf(e0, e1) + bA;
        if (nA < P_N) mfA = fmaxf(mfA, 0.f);         // masked rows: x = 0
        out[(size_t)vA * 64 + lane] = fmaxf(mfA + bias, 0.f);

        // voxel B
        float g0 = -3.4e38f, g1 = -3.4e38f;
        {
            int p = 0;
            for (; p + 1 < nB; p += 2) {
                const float d0 = DOT(p, 32);
                const float d1 = DOT(p + 1, 32);
                g0 = fmaxf(g0, d0);
                g1 = fmaxf(g1, d1);
            }
            if (p < nB) g0 = fmaxf(g0, DOT(p, 32));
        }
        float mfB = fmaxf(g0, g1) + bB;
        if (nB < P_N) mfB = fmaxf(mfB, 0.f);
        out[(size_t)vB * 64 + lane] = fmaxf(mfB + bias, 0.f);
    }
#undef DOT
}

// ---------------------------------------------------------------------------
extern "C" void kernel_launch(void* const* d_in, const int* in_sizes, int n_in,
                              void* d_out, int out_size, void* d_ws, size_t ws_size,
                              hipStream_t stream)
{
    const float4* voxels = (const float4*)d_in[0];
    const int*    npts   = (const int*)d_in[1];
    const int*    coors  = (const int*)d_in[2];
    const float*  W      = (const float*)d_in[3];
    const float*  gamma  = (const float*)d_in[4];
    const float*  beta   = (const float*)d_in[5];
    float*        out    = (float*)d_out;

    float*  stats = (float*)d_ws;                        // padded counters
    float4* means = (float4*)((char*)d_ws + 8192);

    hipMemsetAsync(stats, 0, 54 * CSTR * sizeof(float), stream);
    stats_kernel<<<SBLK, 256, 0, stream>>>(voxels, npts, coors, stats, means);
    pfn_kernel<<<PBLK, 256, 0, stream>>>(voxels, npts, coors, W, gamma, beta,
                                         stats, means, out);
}